// Round 1
// 444.247 us; speedup vs baseline: 1.0606x; 1.0606x over previous
//
#include <hip/hip_runtime.h>
#include <hip/hip_bf16.h>
#include <math.h>

typedef unsigned short u16;
typedef __attribute__((ext_vector_type(8))) short short8;
typedef __attribute__((ext_vector_type(4))) float floatx4;

__device__ __forceinline__ float lk(float v){ return v >= 0.f ? v : 0.01f*v; }
__device__ __forceinline__ u16 f2b(float f){
    __hip_bfloat16 h = __float2bfloat16(f);
    return *reinterpret_cast<u16*>(&h);
}
__device__ __forceinline__ int refl12288(int t){
    return t < 0 ? -t : (t >= 12288 ? 2*12288-2-t : t);
}

// ---------------------------------------------------------------------------
// Hypernet conv1 (MFMA bf16, positions-on-M), v2:
//  - 2 tiles/block, double-buffered LDS, async-STAGE split (loads to regs
//    issued before compute of previous tile -> HBM latency hidden).
//  - h1 output layout changed to [b][3072 pos][32 ch] bf16 -> 32B-segment
//    stores here and fully-vectorized staging reads in k_hconv2.
// ---------------------------------------------------------------------------
__global__ __launch_bounds__(256,3) void k_hconv1(const float* __restrict__ x,
        const float* __restrict__ w, const float* __restrict__ bias,
        u16* __restrict__ h1)
{
    __shared__ __align__(16) u16 xs[2][520*24];
    int b = blockIdx.x / 12, pb = blockIdx.x % 12;
    int tid = threadIdx.x;
    const float* xb = x + (size_t)b*16*12288;
    int wv = tid >> 6, lane = tid & 63;
    int m = lane & 15, kq = lane >> 4;
    int ohalf = wv & 1, thalf = wv >> 1;
    int o = ohalf*16 + m;                      // B-frag n-dim = output channel

    short8 wfr[4];
    #pragma unroll
    for (int s=0;s<4;s++){
        int tap = 2*s + (kq>>1);
        #pragma unroll
        for (int j=0;j<8;j++){
            int ic = (kq&1)*8 + j;
            wfr[s][j] = (tap < 7) ? (short)f2b(w[(o*16+ic)*7 + tap]) : (short)0;
        }
    }

    float rg0[16], rg1[16], rg2[16];

#define LOADTILE(G0) { \
        int t0 = refl12288((G0) - 3 + tid); \
        int t1 = refl12288((G0) - 3 + tid + 256); \
        _Pragma("unroll") \
        for (int ic=0;ic<16;ic++){ \
            rg0[ic] = xb[(size_t)ic*12288 + t0]; \
            rg1[ic] = xb[(size_t)ic*12288 + t1]; \
        } \
        if (tid < 8){ \
            int t2 = refl12288((G0) - 3 + 512 + tid); \
            _Pragma("unroll") \
            for (int ic=0;ic<16;ic++) rg2[ic] = xb[(size_t)ic*12288 + t2]; \
        } }

#define WRITETILE(BUF) { \
        short8 p0, p1; \
        _Pragma("unroll") \
        for (int j=0;j<8;j++){ p0[j] = (short)f2b(rg0[j]); p1[j] = (short)f2b(rg0[8+j]); } \
        *reinterpret_cast<short8*>(&xs[BUF][tid*24])     = p0; \
        *reinterpret_cast<short8*>(&xs[BUF][tid*24 + 8]) = p1; \
        _Pragma("unroll") \
        for (int j=0;j<8;j++){ p0[j] = (short)f2b(rg1[j]); p1[j] = (short)f2b(rg1[8+j]); } \
        *reinterpret_cast<short8*>(&xs[BUF][(tid+256)*24])     = p0; \
        *reinterpret_cast<short8*>(&xs[BUF][(tid+256)*24 + 8]) = p1; \
        if (tid < 8){ \
            _Pragma("unroll") \
            for (int j=0;j<8;j++){ p0[j] = (short)f2b(rg2[j]); p1[j] = (short)f2b(rg2[8+j]); } \
            *reinterpret_cast<short8*>(&xs[BUF][(512+tid)*24])     = p0; \
            *reinterpret_cast<short8*>(&xs[BUF][(512+tid)*24 + 8]) = p1; \
        } }

#define COMPUTESTORE(BUF, TILE) { \
        floatx4 acc[16]; \
        _Pragma("unroll") \
        for (int i=0;i<16;i++) acc[i] = (floatx4){0.f,0.f,0.f,0.f}; \
        int tb0 = thalf*256; \
        _Pragma("unroll") \
        for (int sub=0; sub<16; sub++){ \
            int tb = tb0 + sub*16; \
            _Pragma("unroll") \
            for (int s=0;s<4;s++){ \
                int tap = 2*s + (kq>>1); \
                short8 xfr = *reinterpret_cast<const short8*>( \
                                &xs[BUF][(tb + m + tap)*24 + (kq&1)*8]); \
                acc[sub] = __builtin_amdgcn_mfma_f32_16x16x32_bf16(xfr, wfr[s], acc[sub], 0,0,0); \
            } \
        } \
        float bv = bias[o]; \
        size_t base = ((size_t)b*3072 + (TILE)*128 + thalf*64 + kq)*32 + o; \
        _Pragma("unroll") \
        for (int sub=0; sub<16; sub++){ \
            float sum = lk(acc[sub][0]+bv) + lk(acc[sub][1]+bv) \
                      + lk(acc[sub][2]+bv) + lk(acc[sub][3]+bv); \
            h1[base + (size_t)sub*128] = f2b(sum*0.25f); \
        } }

    int g0 = pb*1024;
    LOADTILE(g0);
    WRITETILE(0);
    __syncthreads();
    LOADTILE(g0 + 512);          // issued before compute -> latency hidden
    COMPUTESTORE(0, pb*2);
    WRITETILE(1);                // waits vmcnt here, after ~2000cy of MFMA
    __syncthreads();
    COMPUTESTORE(1, pb*2 + 1);

#undef LOADTILE
#undef WRITETILE
#undef COMPUTESTORE
}

// ---------------------------------------------------------------------------
// Hypernet conv2 (MFMA bf16, positions-on-M): h1 bf16 [b][3072][32] ->
// h2 f32 [128,64,768].  Staging is now a pure vectorized copy (short8),
// no per-element gather/repack.
// ---------------------------------------------------------------------------
__global__ __launch_bounds__(256,1) void k_hconv2(const u16* __restrict__ h1,
        const float* __restrict__ w, const float* __restrict__ bias,
        float* __restrict__ h2)
{
    __shared__ __align__(16) u16 xs[390*40];
    int b = blockIdx.x >> 3, tile = blockIdx.x & 7;
    int g0 = tile*384;
    int tid = threadIdx.x;
    for (int idx = tid; idx < 390*4; idx += 256){
        int row = idx >> 2, q = idx & 3;
        int t = g0 + row - 3;
        t = t < 0 ? -t : (t >= 3072 ? 2*3072-2-t : t);
        *reinterpret_cast<short8*>(&xs[row*40 + q*8]) =
            *reinterpret_cast<const short8*>(&h1[((size_t)b*3072 + t)*32 + q*8]);
    }
    __syncthreads();
    int wv = tid >> 6, lane = tid & 63;
    int m = lane & 15, kq = lane >> 4;
    int o = wv*16 + m;
    short8 wfr[7];
    #pragma unroll
    for (int s=0;s<7;s++){
        #pragma unroll
        for (int j=0;j<8;j++)
            wfr[s][j] = (short)f2b(w[(size_t)(o*32 + kq*8 + j)*7 + s]);
    }
    floatx4 acc[24];
    #pragma unroll
    for (int i=0;i<24;i++) acc[i] = (floatx4){0.f,0.f,0.f,0.f};
    for (int sub=0; sub<24; sub++){
        int tb = sub*16;
        #pragma unroll
        for (int s=0;s<7;s++){
            short8 xfr = *reinterpret_cast<const short8*>(
                            &xs[(tb + m + s)*40 + kq*8]);
            acc[sub] = __builtin_amdgcn_mfma_f32_16x16x32_bf16(xfr, wfr[s], acc[sub], 0,0,0);
        }
    }
    float bv = bias[o];
    size_t rowbase = (size_t)(b*64 + o)*768 + tile*96 + kq;
    #pragma unroll
    for (int sub=0; sub<24; sub++){
        float sum = lk(acc[sub][0]+bv) + lk(acc[sub][1]+bv)
                  + lk(acc[sub][2]+bv) + lk(acc[sub][3]+bv);
        h2[rowbase + sub*4] = sum*0.25f;
    }
}

// ---------------------------------------------------------------------------
// Hypernet conv3 FUSED: h2 f32 -> latent[128,6144]. (unchanged)
// ---------------------------------------------------------------------------
__global__ __launch_bounds__(256) void k_hconv3(const float* __restrict__ h2,
        const float* __restrict__ w, const float* __restrict__ bias,
        float* __restrict__ latent)
{
    __shared__ float xs[64*200];
    int b = blockIdx.x >> 2, tile = blockIdx.x & 3;
    int g0 = tile*192;
    int tid = threadIdx.x;
    const float* hb = h2 + (size_t)b*64*768;
    for (int idx = tid; idx < 64*198; idx += 256){
        int ic = idx / 198, jj = idx - ic*198;
        int t = g0 + jj - 3;
        t = t < 0 ? -t : (t >= 768 ? 2*768-2-t : t);
        xs[ic*200 + jj] = hb[(size_t)ic*768 + t];
    }
    __syncthreads();
    int c = tid >> 5, run = tid & 31;
    int p0 = run*6;
    float acc[6];
    #pragma unroll
    for (int l=0;l<6;l++) acc[l] = 0.f;
    for (int ic=0; ic<64; ic++){
        const float* wp = w + (c*64+ic)*7;
        float wr[7];
        #pragma unroll
        for (int s=0;s<7;s++) wr[s] = wp[s];
        const float* xr = xs + ic*200 + p0;
        float xw[12];
        #pragma unroll
        for (int j=0;j<12;j++) xw[j] = xr[j];
        #pragma unroll
        for (int s=0;s<7;s++)
            #pragma unroll
            for (int l=0;l<6;l++) acc[l] += wr[s]*xw[l+s];
    }
    float bv = bias[c];
    float* op = latent + (size_t)b*6144 + c*768 + g0 + p0;
    #pragma unroll
    for (int l=0;l<6;l++) op[l] = tanhf(acc[l] + bv);
}

// ---------------------------------------------------------------------------
// t1 = leaky(latent @ hl1^T).  (unchanged)
// ---------------------------------------------------------------------------
__global__ __launch_bounds__(256) void k_lin1(const float* __restrict__ latent,
        const float* __restrict__ hl1, float* __restrict__ t1)
{
    __shared__ float ls[6144];
    int b = blockIdx.x / 6, ntile = blockIdx.x % 6;
    int tid = threadIdx.x;
    const float4* lp = reinterpret_cast<const float4*>(latent + (size_t)b*6144);
    float4* lsv = reinterpret_cast<float4*>(ls);
    for (int i = tid; i < 1536; i += 256) lsv[i] = lp[i];
    __syncthreads();
    int wv = tid >> 6, lane = tid & 63;
    #pragma unroll
    for (int nn=0; nn<4; nn++){
        int n = ntile*16 + wv*4 + nn;
        const float4* wp = reinterpret_cast<const float4*>(hl1 + (size_t)n*6144);
        float s = 0.f;
        #pragma unroll
        for (int j=0;j<24;j++){
            float4 q = wp[lane + 64*j];
            float4 l4 = lsv[lane + 64*j];
            s += l4.x*q.x + l4.y*q.y + l4.z*q.z + l4.w*q.w;
        }
        #pragma unroll
        for (int off=32; off; off>>=1) s += __shfl_down(s, off);
        if (lane==0) t1[b*96+n] = lk(s);
    }
}

// ---------------------------------------------------------------------------
// logits = t1 @ hl2^T; top-5; n0 = #(idx<6)   (unchanged)
// ---------------------------------------------------------------------------
__global__ __launch_bounds__(128) void k_topk(const float* __restrict__ t1,
        const float* __restrict__ hl2, int* __restrict__ idxb, float* __restrict__ n0f)
{
    __shared__ float lg[96];
    int b = blockIdx.x, n = threadIdx.x;
    if (n < 96){
        float s = 0.f;
        const float* tp = t1 + b*96;
        const float* wp = hl2 + n*96;
        for (int m=0;m<96;m++) s += tp[m]*wp[m];
        lg[n] = s;
    }
    __syncthreads();
    if (threadIdx.x == 0){
        unsigned long long u0=0ull, u1=0ull;
        float n0 = 0.f;
        for (int k=0;k<5;k++){
            float best = -3.4e38f; int bi = 0;
            for (int m=0;m<96;m++){
                bool used = m<64 ? ((u0>>m)&1ull) : ((u1>>(m-64))&1ull);
                if (!used && lg[m] > best){ best = lg[m]; bi = m; }
            }
            if (bi<64) u0 |= 1ull<<bi; else u1 |= 1ull<<(bi-64);
            idxb[b*5+k] = bi;
            if (bi < 6) n0 += 1.f;
        }
        n0f[b] = n0;
    }
}

// ---------------------------------------------------------------------------
// Grouped idx conv ks=15 + bias + leaky + maxpool4 -> zp bf16 (unchanged)
// ---------------------------------------------------------------------------
__global__ __launch_bounds__(256) void k_gconv(const float* __restrict__ x,
        const int* __restrict__ idxb, const float* __restrict__ n0f,
        const float* __restrict__ gw, const float* __restrict__ gb0,
        u16* __restrict__ zp)
{
    __shared__ float xs[5][522];
    int b = blockIdx.x >> 2, qc = blockIdx.x & 3;
    int tid = threadIdx.x;
    int l0 = qc*508;
    for (int j=tid; j<5*522; j+=256){
        int k = j/522, u = j - k*522;
        int n = idxb[b*5+k];
        xs[k][u] = x[(size_t)b*196608 + n*2048 + l0 + u];
    }
    __syncthreads();
    int o = tid >> 2, qs = tid & 3;
    float wreg[5][15];
    #pragma unroll
    for (int k=0;k<5;k++){
        int n = idxb[b*5+k]; int gi = n/6;
        const float* wp = gw + gi*960 + o*15;
        #pragma unroll
        for (int s=0;s<15;s++) wreg[k][s] = wp[s];
    }
    float bv = n0f[b]*gb0[o];
    for (int q=qs; q<127; q+=4){
        int lb = 4*q;
        float s0=bv, s1=bv, s2=bv, s3=bv;
        #pragma unroll
        for (int k=0;k<5;k++){
            float xw[18];
            #pragma unroll
            for (int j=0;j<18;j++) xw[j] = xs[k][lb+j];
            #pragma unroll
            for (int sp=0;sp<15;sp++){
                s0 += wreg[k][sp]*xw[sp];
                s1 += wreg[k][sp]*xw[sp+1];
                s2 += wreg[k][sp]*xw[sp+2];
                s3 += wreg[k][sp]*xw[sp+3];
            }
        }
        float mx = fmaxf(fmaxf(lk(s0),lk(s1)), fmaxf(lk(s2),lk(s3)));
        zp[((size_t)(b*64+o))*508 + qc*127 + q] = f2b(mx);
    }
}

// ---------------------------------------------------------------------------
// Encoder conv2 (MFMA bf16, positions-on-M): zp bf16 -> p2 f32 [128,128,125].
// ---------------------------------------------------------------------------
__global__ __launch_bounds__(256,1) void k_econv2(const u16* __restrict__ zp,
        const float* __restrict__ w, const float* __restrict__ bias,
        float* __restrict__ p2)
{
    __shared__ __align__(16) u16 xs[118*72];
    int b = blockIdx.x / 5, tile = blockIdx.x % 5;
    int tid = threadIdx.x;
    if (tid < 118){
        int t = tile*100 + tid; if (t > 507) t = 507;
        u16 v[64];
        #pragma unroll
        for (int ic=0;ic<64;ic++) v[ic] = zp[(size_t)(b*64+ic)*508 + t];
        #pragma unroll
        for (int q=0;q<8;q++){
            short8 p;
            #pragma unroll
            for (int j=0;j<8;j++) p[j] = (short)v[q*8+j];
            *reinterpret_cast<short8*>(&xs[tid*72 + q*8]) = p;
        }
    }
    __syncthreads();
    int wv = tid >> 6, lane = tid & 63;
    int m = lane & 15, kq = lane >> 4;
    for (int half=0; half<2; half++){
        int ot = wv + 4*half;
        int o = ot*16 + m;
        short8 wfr[14];
        #pragma unroll
        for (int s=0;s<14;s++){
            int ih = s/7, tap = s%7;
            #pragma unroll
            for (int j=0;j<8;j++)
                wfr[s][j] = (short)f2b(w[(size_t)(o*64 + ih*32 + kq*8 + j)*7 + tap]);
        }
        floatx4 acc[7];
        #pragma unroll
        for (int i=0;i<7;i++) acc[i] = (floatx4){0.f,0.f,0.f,0.f};
        #pragma unroll
        for (int sub=0; sub<7; sub++){
            #pragma unroll
            for (int s=0;s<14;s++){
                int ih = s/7, tap = s%7;
                short8 xfr = *reinterpret_cast<const short8*>(
                                &xs[(sub*16 + m + tap)*72 + ih*32 + kq*8]);
                acc[sub] = __builtin_amdgcn_mfma_f32_16x16x32_bf16(xfr, wfr[s], acc[sub], 0,0,0);
            }
        }
        float bv = bias[o];
        #pragma unroll
        for (int sub=0; sub<7; sub++){
            int pidx = sub*4 + kq;
            if (pidx < 25){
                float mx = fmaxf(fmaxf(lk(acc[sub][0]+bv), lk(acc[sub][1]+bv)),
                                 fmaxf(lk(acc[sub][2]+bv), lk(acc[sub][3]+bv)));
                p2[(size_t)(b*128 + o)*125 + tile*25 + pidx] = mx;
            }
        }
    }
}

// ---------------------------------------------------------------------------
// Sliding column sums (unchanged)
// ---------------------------------------------------------------------------
__global__ __launch_bounds__(256) void k_colsum(const float* __restrict__ p2,
        float* __restrict__ ssum)
{
    int g = blockIdx.x*256 + threadIdx.x;
    int ic = g & 127, b = g >> 7;
    const float* pp = p2 + ((size_t)(b*128+ic))*125;
    float c = 0.f;
    for (int t=0;t<119;t++) c += pp[t];
    float* op = ssum + (size_t)(b*128+ic)*7;
    op[0] = c;
    #pragma unroll
    for (int s=0;s<6;s++){ c = c - pp[s] + pp[s+119]; op[s+1] = c; }
}

__global__ __launch_bounds__(128) void k_feat(const float* __restrict__ ssum,
        const float* __restrict__ w, const float* __restrict__ bias,
        float* __restrict__ feat)
{
    __shared__ float ss[896];
    int b = blockIdx.x, o = threadIdx.x;
    for (int j=threadIdx.x; j<896; j+=128) ss[j] = ssum[(size_t)b*896 + j];
    __syncthreads();
    const float* wp = w + o*896;
    float s = 0.f;
    for (int j=0;j<896;j++) s += wp[j]*ss[j];
    feat[b*128+o] = s*(1.f/119.f) + bias[o];
}

__global__ __launch_bounds__(64) void k_cls(const float* __restrict__ feat,
        const float* __restrict__ cw, const float* __restrict__ cb,
        float* __restrict__ out)
{
    __shared__ float lg[5];
    int b = blockIdx.x;
    if (threadIdx.x < 5){
        const float* fp = feat + b*128;
        const float* wp = cw + threadIdx.x*128;
        float s = 0.f;
        for (int o=0;o<128;o++) s += fp[o]*wp[o];
        lg[threadIdx.x] = s + cb[threadIdx.x];
    }
    __syncthreads();
    if (threadIdx.x == 0){
        float mx = -3.4e38f;
        for (int c=0;c<5;c++) mx = fmaxf(mx, lg[c]);
        float se = 0.f;
        for (int c=0;c<5;c++) se += expf(lg[c]-mx);
        float lse = mx + logf(se);
        for (int c=0;c<5;c++) out[b*5+c] = lg[c]-lse;
    }
}

extern "C" void kernel_launch(void* const* d_in, const int* in_sizes, int n_in,
                              void* d_out, int out_size, void* d_ws, size_t ws_size,
                              hipStream_t stream)
{
    const float* x   = (const float*)d_in[0];
    const float* hw1 = (const float*)d_in[2];
    const float* hb1 = (const float*)d_in[3];
    const float* hw2 = (const float*)d_in[4];
    const float* hb2 = (const float*)d_in[5];
    const float* hw3 = (const float*)d_in[6];
    const float* hb3 = (const float*)d_in[7];
    const float* hl1 = (const float*)d_in[8];
    const float* hl2 = (const float*)d_in[9];
    const float* gw  = (const float*)d_in[10];
    const float* gb0 = (const float*)d_in[11];
    const float* ew2 = (const float*)d_in[12];
    const float* eb2 = (const float*)d_in[13];
    const float* ew3 = (const float*)d_in[14];
    const float* eb3 = (const float*)d_in[15];
    const float* cw  = (const float*)d_in[16];
    const float* cb  = (const float*)d_in[17];
    float* out = (float*)d_out;

    float* f       = (float*)d_ws;
    float* latent  = f;
    float* h2      = f + 3932160;
    u16*   h1b     = (u16*)(f + 10223616);
    float* t1      = f + 786432;
    int*   idxb    = (int*)(f + 806432);
    float* n0f     = f + 808432;
    u16*   zpb     = (u16*)(f + 810000);
    float* p2      = f + 5000000;
    float* ssum    = f + 7100000;
    float* feat    = f + 7300000;

    k_hconv1<<<1536, 256, 0, stream>>>(x, hw1, hb1, h1b);
    k_hconv2<<<1024, 256, 0, stream>>>(h1b, hw2, hb2, h2);
    k_hconv3<<<512, 256, 0, stream>>>(h2, hw3, hb3, latent);
    k_lin1<<<768, 256, 0, stream>>>(latent, hl1, t1);
    k_topk<<<128, 128, 0, stream>>>(t1, hl2, idxb, n0f);
    k_gconv<<<512, 256, 0, stream>>>(x, idxb, n0f, gw, gb0, zpb);
    k_econv2<<<640, 256, 0, stream>>>(zpb, ew2, eb2, p2);
    k_colsum<<<64, 256, 0, stream>>>(p2, ssum);
    k_feat<<<128, 128, 0, stream>>>(ssum, ew3, eb3, feat);
    k_cls<<<128, 64, 0, stream>>>(feat, cw, cb, out);
}

// Round 2
// 407.790 us; speedup vs baseline: 1.1554x; 1.0894x over previous
//
#include <hip/hip_runtime.h>
#include <hip/hip_bf16.h>
#include <math.h>

typedef unsigned short u16;
typedef __attribute__((ext_vector_type(8))) short short8;
typedef __attribute__((ext_vector_type(4))) float floatx4;

__device__ __forceinline__ float lk(float v){ return v >= 0.f ? v : 0.01f*v; }
__device__ __forceinline__ u16 f2b(float f){
    __hip_bfloat16 h = __float2bfloat16(f);
    return *reinterpret_cast<u16*>(&h);
}
__device__ __forceinline__ int refl(int t, int L){
    return t < 0 ? -t : (t >= L ? 2*L-2-t : t);
}

// ---------------------------------------------------------------------------
// Hypernet conv1: x[128,16,12288] f32 -> h1 bf16 [b][3072 pos][32 ch].
// v3: tile=256 (2 tiles/block, dbuf, async split), LDS 25.3KB, acc[8]
// -> 6 blocks/CU for latency overlap across blocks.
// ---------------------------------------------------------------------------
__global__ __launch_bounds__(256,6) void k_hconv1(const float* __restrict__ x,
        const float* __restrict__ w, const float* __restrict__ bias,
        u16* __restrict__ h1)
{
    __shared__ __align__(16) u16 xs[2][264*24];
    int b = blockIdx.x / 24, pb = blockIdx.x % 24;
    int tid = threadIdx.x;
    const float* xb = x + (size_t)b*16*12288;
    int wv = tid >> 6, lane = tid & 63;
    int m = lane & 15, kq = lane >> 4;
    int ohalf = wv & 1, thalf = wv >> 1;
    int o = ohalf*16 + m;

    short8 wfr[4];
    #pragma unroll
    for (int s=0;s<4;s++){
        int tap = 2*s + (kq>>1);
        #pragma unroll
        for (int j=0;j<8;j++){
            int ic = (kq&1)*8 + j;
            wfr[s][j] = (tap < 7) ? (short)f2b(w[(o*16+ic)*7 + tap]) : (short)0;
        }
    }

    float rg0[16]; float rgx;
    int exrow = 256 + (tid>>4), exch = tid & 15;   // threads 0..127 load 8 extra rows

#define LOADTILE(G0) { \
        int t0 = refl((G0) - 3 + tid, 12288); \
        _Pragma("unroll") \
        for (int ic=0;ic<16;ic++) rg0[ic] = xb[(size_t)ic*12288 + t0]; \
        if (tid < 128){ \
            int t1 = refl((G0) - 3 + exrow, 12288); \
            rgx = xb[(size_t)exch*12288 + t1]; \
        } }

#define WRITETILE(BUF) { \
        short8 p0, p1; \
        _Pragma("unroll") \
        for (int j=0;j<8;j++){ p0[j] = (short)f2b(rg0[j]); p1[j] = (short)f2b(rg0[8+j]); } \
        *reinterpret_cast<short8*>(&xs[BUF][tid*24])     = p0; \
        *reinterpret_cast<short8*>(&xs[BUF][tid*24 + 8]) = p1; \
        if (tid < 128) xs[BUF][exrow*24 + exch] = f2b(rgx); }

#define COMPUTESTORE(BUF, TILE) { \
        floatx4 acc[8]; \
        _Pragma("unroll") \
        for (int i=0;i<8;i++) acc[i] = (floatx4){0.f,0.f,0.f,0.f}; \
        int tb0 = thalf*128; \
        _Pragma("unroll") \
        for (int sub=0; sub<8; sub++){ \
            int tb = tb0 + sub*16; \
            _Pragma("unroll") \
            for (int s=0;s<4;s++){ \
                int tap = 2*s + (kq>>1); \
                short8 xfr = *reinterpret_cast<const short8*>( \
                                &xs[BUF][(tb + m + tap)*24 + (kq&1)*8]); \
                acc[sub] = __builtin_amdgcn_mfma_f32_16x16x32_bf16(xfr, wfr[s], acc[sub], 0,0,0); \
            } \
        } \
        float bv = bias[o]; \
        size_t base = ((size_t)b*3072 + (TILE)*64 + thalf*32 + kq)*32 + o; \
        _Pragma("unroll") \
        for (int sub=0; sub<8; sub++){ \
            float sum = lk(acc[sub][0]+bv) + lk(acc[sub][1]+bv) \
                      + lk(acc[sub][2]+bv) + lk(acc[sub][3]+bv); \
            h1[base + (size_t)sub*128] = f2b(sum*0.25f); \
        } }

    int g0 = pb*512;
    LOADTILE(g0);
    WRITETILE(0);
    __syncthreads();
    LOADTILE(g0 + 256);
    COMPUTESTORE(0, pb*2);
    WRITETILE(1);
    __syncthreads();
    COMPUTESTORE(1, pb*2 + 1);

#undef LOADTILE
#undef WRITETILE
#undef COMPUTESTORE
}

// ---------------------------------------------------------------------------
// Hypernet conv2: h1 bf16 [b][3072][32] -> h2 f32 [b][768 pos][64 ch].
// v2: 2x192 halves, dbuf, async split, acc[12] -> ~4 blocks/CU.
// ---------------------------------------------------------------------------
__global__ __launch_bounds__(256,4) void k_hconv2(const u16* __restrict__ h1,
        const float* __restrict__ w, const float* __restrict__ bias,
        float* __restrict__ h2)
{
    __shared__ __align__(16) u16 xs[2][198*40];
    int b = blockIdx.x >> 3, tile = blockIdx.x & 7;
    int tid = threadIdx.x;
    int wv = tid >> 6, lane = tid & 63;
    int m = lane & 15, kq = lane >> 4;
    int o = wv*16 + m;

    short8 wfr[7];
    #pragma unroll
    for (int s=0;s<7;s++){
        #pragma unroll
        for (int j=0;j<8;j++)
            wfr[s][j] = (short)f2b(w[(size_t)(o*32 + kq*8 + j)*7 + s]);
    }

    short8 rgA[3], rgX;

#define LOADH(HALF) { \
        int gh = tile*384 + (HALF)*192 - 3; \
        _Pragma("unroll") \
        for (int cc=0;cc<3;cc++){ \
            int c = tid + cc*256; \
            int row = c >> 2, q = c & 3; \
            int t = refl(gh + row, 3072); \
            rgA[cc] = *reinterpret_cast<const short8*>(&h1[((size_t)b*3072 + t)*32 + q*8]); \
        } \
        if (tid < 24){ \
            int c = 768 + tid; \
            int row = c >> 2, q = c & 3; \
            int t = refl(gh + row, 3072); \
            rgX = *reinterpret_cast<const short8*>(&h1[((size_t)b*3072 + t)*32 + q*8]); \
        } }

#define WRITEH(BUF) { \
        _Pragma("unroll") \
        for (int cc=0;cc<3;cc++){ \
            int c = tid + cc*256; \
            *reinterpret_cast<short8*>(&xs[BUF][(c>>2)*40 + (c&3)*8]) = rgA[cc]; \
        } \
        if (tid < 24){ \
            int c = 768 + tid; \
            *reinterpret_cast<short8*>(&xs[BUF][(c>>2)*40 + (c&3)*8]) = rgX; \
        } }

#define COMPUTEH(BUF, HALF) { \
        floatx4 acc[12]; \
        _Pragma("unroll") \
        for (int i=0;i<12;i++) acc[i] = (floatx4){0.f,0.f,0.f,0.f}; \
        for (int sub=0; sub<12; sub++){ \
            int tb = sub*16; \
            _Pragma("unroll") \
            for (int s=0;s<7;s++){ \
                short8 xfr = *reinterpret_cast<const short8*>( \
                                &xs[BUF][(tb + m + s)*40 + kq*8]); \
                acc[sub] = __builtin_amdgcn_mfma_f32_16x16x32_bf16(xfr, wfr[s], acc[sub], 0,0,0); \
            } \
        } \
        float bv = bias[o]; \
        _Pragma("unroll") \
        for (int sub=0; sub<12; sub++){ \
            float sum = lk(acc[sub][0]+bv) + lk(acc[sub][1]+bv) \
                      + lk(acc[sub][2]+bv) + lk(acc[sub][3]+bv); \
            h2[((size_t)b*768 + tile*96 + (HALF)*48 + sub*4 + kq)*64 + o] = sum*0.25f; \
        } }

    LOADH(0);
    WRITEH(0);
    __syncthreads();
    LOADH(1);
    COMPUTEH(0, 0);
    WRITEH(1);
    __syncthreads();
    COMPUTEH(1, 1);

#undef LOADH
#undef WRITEH
#undef COMPUTEH
}

// ---------------------------------------------------------------------------
// Hypernet conv3 FUSED: h2 f32 [b][768][64] -> latent[128,6144].
// Staging is now coalesced reads + transposed LDS write (stride 201, no
// 16-way conflicts).
// ---------------------------------------------------------------------------
__global__ __launch_bounds__(256) void k_hconv3(const float* __restrict__ h2,
        const float* __restrict__ w, const float* __restrict__ bias,
        float* __restrict__ latent)
{
    __shared__ float xs[64*201];
    int b = blockIdx.x >> 2, tile = blockIdx.x & 3;
    int g0 = tile*192;
    int tid = threadIdx.x;
    for (int idx = tid; idx < 198*64; idx += 256){
        int jj = idx >> 6, ic = idx & 63;
        int t = refl(g0 + jj - 3, 768);
        xs[ic*201 + jj] = h2[((size_t)b*768 + t)*64 + ic];
    }
    __syncthreads();
    int c = tid >> 5, run = tid & 31;
    int p0 = run*6;
    float acc[6];
    #pragma unroll
    for (int l=0;l<6;l++) acc[l] = 0.f;
    for (int ic=0; ic<64; ic++){
        const float* wp = w + (c*64+ic)*7;
        float wr[7];
        #pragma unroll
        for (int s=0;s<7;s++) wr[s] = wp[s];
        const float* xr = xs + ic*201 + p0;
        float xw[12];
        #pragma unroll
        for (int j=0;j<12;j++) xw[j] = xr[j];
        #pragma unroll
        for (int s=0;s<7;s++)
            #pragma unroll
            for (int l=0;l<6;l++) acc[l] += wr[s]*xw[l+s];
    }
    float bv = bias[c];
    float* op = latent + (size_t)b*6144 + c*768 + g0 + p0;
    #pragma unroll
    for (int l=0;l<6;l++) op[l] = tanhf(acc[l] + bv);
}

// ---------------------------------------------------------------------------
// t1 = leaky(latent @ hl1^T).  (unchanged)
// ---------------------------------------------------------------------------
__global__ __launch_bounds__(256) void k_lin1(const float* __restrict__ latent,
        const float* __restrict__ hl1, float* __restrict__ t1)
{
    __shared__ float ls[6144];
    int b = blockIdx.x / 6, ntile = blockIdx.x % 6;
    int tid = threadIdx.x;
    const float4* lp = reinterpret_cast<const float4*>(latent + (size_t)b*6144);
    float4* lsv = reinterpret_cast<float4*>(ls);
    for (int i = tid; i < 1536; i += 256) lsv[i] = lp[i];
    __syncthreads();
    int wv = tid >> 6, lane = tid & 63;
    #pragma unroll
    for (int nn=0; nn<4; nn++){
        int n = ntile*16 + wv*4 + nn;
        const float4* wp = reinterpret_cast<const float4*>(hl1 + (size_t)n*6144);
        float s = 0.f;
        #pragma unroll
        for (int j=0;j<24;j++){
            float4 q = wp[lane + 64*j];
            float4 l4 = lsv[lane + 64*j];
            s += l4.x*q.x + l4.y*q.y + l4.z*q.z + l4.w*q.w;
        }
        #pragma unroll
        for (int off=32; off; off>>=1) s += __shfl_down(s, off);
        if (lane==0) t1[b*96+n] = lk(s);
    }
}

// ---------------------------------------------------------------------------
// logits = t1 @ hl2^T; top-5; n0 = #(idx<6)   (unchanged)
// ---------------------------------------------------------------------------
__global__ __launch_bounds__(128) void k_topk(const float* __restrict__ t1,
        const float* __restrict__ hl2, int* __restrict__ idxb, float* __restrict__ n0f)
{
    __shared__ float lg[96];
    int b = blockIdx.x, n = threadIdx.x;
    if (n < 96){
        float s = 0.f;
        const float* tp = t1 + b*96;
        const float* wp = hl2 + n*96;
        for (int m=0;m<96;m++) s += tp[m]*wp[m];
        lg[n] = s;
    }
    __syncthreads();
    if (threadIdx.x == 0){
        unsigned long long u0=0ull, u1=0ull;
        float n0 = 0.f;
        for (int k=0;k<5;k++){
            float best = -3.4e38f; int bi = 0;
            for (int m=0;m<96;m++){
                bool used = m<64 ? ((u0>>m)&1ull) : ((u1>>(m-64))&1ull);
                if (!used && lg[m] > best){ best = lg[m]; bi = m; }
            }
            if (bi<64) u0 |= 1ull<<bi; else u1 |= 1ull<<(bi-64);
            idxb[b*5+k] = bi;
            if (bi < 6) n0 += 1.f;
        }
        n0f[b] = n0;
    }
}

// ---------------------------------------------------------------------------
// Grouped idx conv, MFMA version.  K = 5 windows x 16 taps = 80 (pad 96,
// zeros carried in weight frags).  A-operand (Hankel) read from 8 shifted
// bf16 LDS copies so ds_read_b128 stays 16B-aligned.  Output: conv + bias,
// leaky, in-register maxpool4 -> zp bf16 [b][508 pos][64 oc].
// ---------------------------------------------------------------------------
__global__ __launch_bounds__(256,3) void k_gconv(const float* __restrict__ x,
        const int* __restrict__ idxb, const float* __restrict__ n0f,
        const float* __restrict__ gw, const float* __restrict__ gb0,
        u16* __restrict__ zp)
{
    __shared__ __align__(16) u16 xs[5][8][536];
    __shared__ int nidx[5];
    __shared__ float n0s;
    int b = blockIdx.x >> 2, qc = blockIdx.x & 3;
    int tid = threadIdx.x;
    int p0g = qc*512;

    if (tid < 5) nidx[tid] = idxb[b*5 + tid];
    if (tid == 5) n0s = n0f[b];
    __syncthreads();

    // Staging: for each window k, read aligned float4 spans of x, scatter
    // bf16 into the 8 shifted copies.
    for (int cch = tid; cch < 5*134; cch += 256){
        int k = cch / 134, q = cch - k*134;
        const float* xrow = x + (size_t)b*196608 + (size_t)nidx[k]*2048;
        int base = p0g + q*4;
        u16 vb[4];
        if (base + 3 <= 2047){
            float4 a = *reinterpret_cast<const float4*>(xrow + base);
            vb[0]=f2b(a.x); vb[1]=f2b(a.y); vb[2]=f2b(a.z); vb[3]=f2b(a.w);
        } else {
            #pragma unroll
            for (int jj=0;jj<4;jj++){
                int ii = base+jj; if (ii > 2047) ii = 2047;
                vb[jj] = f2b(xrow[ii]);
            }
        }
        #pragma unroll
        for (int jj=0;jj<4;jj++){
            int gof = q*4 + jj;
            #pragma unroll
            for (int r=0;r<8;r++){
                int i = gof - r;
                if (i >= 0 && i < 528) xs[k][r][i] = vb[jj];
            }
        }
    }

    int wv = tid >> 6, lane = tid & 63;
    int m = lane & 15, kq = lane >> 4;
    int o = wv*16 + m;           // lane&15 is n for B/C, m for A

    // Weight frags: k = 32c + kq*8 + j -> kk = k>>4, tap = k&15
    short8 wfr[3];
    #pragma unroll
    for (int c=0;c<3;c++){
        #pragma unroll
        for (int j=0;j<8;j++){
            int k = 32*c + kq*8 + j;
            int kk = k >> 4, tap = k & 15;
            short v = 0;
            if (kk < 5 && tap < 15){
                int gi = nidx[kk] / 6;
                v = (short)f2b(gw[(size_t)gi*960 + o*15 + tap]);
            }
            wfr[c][j] = v;
        }
    }
    float bv = n0s * gb0[o];
    __syncthreads();

    int rr = m & 7, ibase = (m & 8) + (kq & 1)*8;
    for (int g8 = 0; g8 < 4; ++g8){
        floatx4 acc[8];
        #pragma unroll
        for (int i=0;i<8;i++) acc[i] = (floatx4){0.f,0.f,0.f,0.f};
        #pragma unroll
        for (int s8=0; s8<8; ++s8){
            int P = (g8*8 + s8)*16;
            #pragma unroll
            for (int c=0;c<3;c++){
                int kk = 2*c + (kq>>1);
                int kkc = kk < 5 ? kk : 4;
                short8 af = *reinterpret_cast<const short8*>(&xs[kkc][rr][P + ibase]);
                acc[s8] = __builtin_amdgcn_mfma_f32_16x16x32_bf16(af, wfr[c], acc[s8], 0,0,0);
            }
        }
        #pragma unroll
        for (int s8=0; s8<8; ++s8){
            int sub = g8*8 + s8;
            int Q = qc*128 + sub*4 + kq;
            if (Q < 508){
                float mx = fmaxf(fmaxf(lk(acc[s8][0]+bv), lk(acc[s8][1]+bv)),
                                 fmaxf(lk(acc[s8][2]+bv), lk(acc[s8][3]+bv)));
                zp[((size_t)b*508 + Q)*64 + o] = f2b(mx);
            }
        }
    }
}

// ---------------------------------------------------------------------------
// Encoder conv2 (MFMA bf16): zp bf16 [b][508][64] -> p2 f32 [b][125][128].
// Staging is now a coalesced short8 copy using all 256 threads.
// ---------------------------------------------------------------------------
__global__ __launch_bounds__(256,1) void k_econv2(const u16* __restrict__ zp,
        const float* __restrict__ w, const float* __restrict__ bias,
        float* __restrict__ p2)
{
    __shared__ __align__(16) u16 xs[118*72];
    int b = blockIdx.x / 5, tile = blockIdx.x % 5;
    int tid = threadIdx.x;
    for (int c = tid; c < 118*8; c += 256){
        int row = c >> 3, q = c & 7;
        int t = tile*100 + row; if (t > 507) t = 507;
        *reinterpret_cast<short8*>(&xs[row*72 + q*8]) =
            *reinterpret_cast<const short8*>(&zp[((size_t)b*508 + t)*64 + q*8]);
    }
    __syncthreads();
    int wv = tid >> 6, lane = tid & 63;
    int m = lane & 15, kq = lane >> 4;
    for (int half=0; half<2; half++){
        int ot = wv + 4*half;
        int o = ot*16 + m;
        short8 wfr[14];
        #pragma unroll
        for (int s=0;s<14;s++){
            int ih = s/7, tap = s%7;
            #pragma unroll
            for (int j=0;j<8;j++)
                wfr[s][j] = (short)f2b(w[(size_t)(o*64 + ih*32 + kq*8 + j)*7 + tap]);
        }
        floatx4 acc[7];
        #pragma unroll
        for (int i=0;i<7;i++) acc[i] = (floatx4){0.f,0.f,0.f,0.f};
        #pragma unroll
        for (int sub=0; sub<7; sub++){
            #pragma unroll
            for (int s=0;s<14;s++){
                int ih = s/7, tap = s%7;
                short8 xfr = *reinterpret_cast<const short8*>(
                                &xs[(sub*16 + m + tap)*72 + ih*32 + kq*8]);
                acc[sub] = __builtin_amdgcn_mfma_f32_16x16x32_bf16(xfr, wfr[s], acc[sub], 0,0,0);
            }
        }
        float bv = bias[o];
        #pragma unroll
        for (int sub=0; sub<7; sub++){
            int pidx = sub*4 + kq;
            if (pidx < 25){
                float mx = fmaxf(fmaxf(lk(acc[sub][0]+bv), lk(acc[sub][1]+bv)),
                                 fmaxf(lk(acc[sub][2]+bv), lk(acc[sub][3]+bv)));
                p2[((size_t)b*125 + tile*25 + pidx)*128 + o] = mx;
            }
        }
    }
}

// ---------------------------------------------------------------------------
// Fused tail: sliding column sums + feat (ew3 conv mean) + classifier +
// log_softmax.  One block per batch element, 128 threads.
// ---------------------------------------------------------------------------
__global__ __launch_bounds__(128) void k_tail(const float* __restrict__ p2,
        const float* __restrict__ w, const float* __restrict__ bias,
        const float* __restrict__ cw, const float* __restrict__ cb,
        float* __restrict__ out)
{
    __shared__ float ss[7][128];
    __shared__ float ft[128];
    __shared__ float lgs[5];
    int b = blockIdx.x, tid = threadIdx.x;

    // phase 1: sliding sums over positions (p2 is [b][125][128])
    {
        const float* pb = p2 + (size_t)b*125*128 + tid;
        float first6[6], last6[6];
        float c = 0.f;
        #pragma unroll
        for (int t=0;t<6;t++){ float v = pb[(size_t)t*128]; first6[t]=v; c+=v; }
        for (int t=6;t<119;t++) c += pb[(size_t)t*128];
        #pragma unroll
        for (int t=0;t<6;t++) last6[t] = pb[(size_t)(119+t)*128];
        ss[0][tid] = c;
        #pragma unroll
        for (int s=0;s<6;s++){ c = c - first6[s] + last6[s]; ss[s+1][tid] = c; }
    }
    __syncthreads();

    // phase 2: feat[o] = (1/119) * sum_{ic,tap} w[o][ic*7+tap]*ss[tap][ic] + bias[o]
    {
        const float* wp = w + (size_t)tid*896;
        float s = 0.f;
        for (int ic=0; ic<128; ic++){
            #pragma unroll
            for (int tp=0; tp<7; tp++)
                s += wp[ic*7+tp]*ss[tp][ic];
        }
        ft[tid] = s*(1.f/119.f) + bias[tid];
    }
    __syncthreads();

    // phase 3: classifier + log_softmax
    if (tid < 5){
        float lg = cb[tid];
        const float* wp = cw + tid*128;
        for (int o=0;o<128;o++) lg += ft[o]*wp[o];
        lgs[tid] = lg;
    }
    __syncthreads();
    if (tid == 0){
        float mx = -3.4e38f;
        for (int c=0;c<5;c++) mx = fmaxf(mx, lgs[c]);
        float se = 0.f;
        for (int c=0;c<5;c++) se += expf(lgs[c]-mx);
        float lse = mx + logf(se);
        for (int c=0;c<5;c++) out[b*5+c] = lgs[c]-lse;
    }
}

extern "C" void kernel_launch(void* const* d_in, const int* in_sizes, int n_in,
                              void* d_out, int out_size, void* d_ws, size_t ws_size,
                              hipStream_t stream)
{
    const float* x   = (const float*)d_in[0];
    const float* hw1 = (const float*)d_in[2];
    const float* hb1 = (const float*)d_in[3];
    const float* hw2 = (const float*)d_in[4];
    const float* hb2 = (const float*)d_in[5];
    const float* hw3 = (const float*)d_in[6];
    const float* hb3 = (const float*)d_in[7];
    const float* hl1 = (const float*)d_in[8];
    const float* hl2 = (const float*)d_in[9];
    const float* gw  = (const float*)d_in[10];
    const float* gb0 = (const float*)d_in[11];
    const float* ew2 = (const float*)d_in[12];
    const float* eb2 = (const float*)d_in[13];
    const float* ew3 = (const float*)d_in[14];
    const float* eb3 = (const float*)d_in[15];
    const float* cw  = (const float*)d_in[16];
    const float* cb  = (const float*)d_in[17];
    float* out = (float*)d_out;

    float* f       = (float*)d_ws;
    float* latent  = f;                       // 786,432 f
    float* t1      = f + 786432;              // 12,288 f
    int*   idxb    = (int*)(f + 806432);
    float* n0f     = f + 808432;
    u16*   zpb     = (u16*)(f + 810000);      // 2,080,768 f
    float* h2      = f + 3932160;             // 6,291,456 f (dead before p2/zp use ends)
    float* p2      = f + 5000000;             // 2,048,000 f (h2 dead by then)
    u16*   h1b     = (u16*)(f + 10223616);    // 6,291,456 f

    k_hconv1<<<3072, 256, 0, stream>>>(x, hw1, hb1, h1b);
    k_hconv2<<<1024, 256, 0, stream>>>(h1b, hw2, hb2, h2);
    k_hconv3<<<512, 256, 0, stream>>>(h2, hw3, hb3, latent);
    k_lin1<<<768, 256, 0, stream>>>(latent, hl1, t1);
    k_topk<<<128, 128, 0, stream>>>(t1, hl2, idxb, n0f);
    k_gconv<<<512, 256, 0, stream>>>(x, idxb, n0f, gw, gb0, zpb);
    k_econv2<<<640, 256, 0, stream>>>(zpb, ew2, eb2, p2);
    k_tail<<<128, 128, 0, stream>>>(p2, ew3, eb3, cw, cb, out);
}

// Round 3
// 358.907 us; speedup vs baseline: 1.3127x; 1.1362x over previous
//
#include <hip/hip_runtime.h>
#include <hip/hip_bf16.h>
#include <math.h>

typedef unsigned short u16;
typedef __attribute__((ext_vector_type(8))) short short8;
typedef __attribute__((ext_vector_type(4))) float floatx4;

__device__ __forceinline__ float lk(float v){ return v >= 0.f ? v : 0.01f*v; }
__device__ __forceinline__ u16 f2b(float f){
    __hip_bfloat16 h = __float2bfloat16(f);
    return *reinterpret_cast<u16*>(&h);
}
__device__ __forceinline__ int refl(int t, int L){
    return t < 0 ? -t : (t >= L ? 2*L-2-t : t);
}

// ---------------------------------------------------------------------------
// Weight pre-conversion: bake all MFMA weight fragments to bf16 in frag
// layout.  wb u16 layout:
//   [0,4096)        wb1  hconv1: (((s*4+kq)*32)+o)*8+j
//   [4096,18432)    wb2  hconv2: (((s*4+kq)*64)+o)*8+j
//   [18432,75776)   wbe  econv2: (((s*4+kq)*128)+o)*8+j
//   [75776,92160)   gwb  gconv:  (((gi*2+tb)*64)+o)*8+j
// ---------------------------------------------------------------------------
__global__ __launch_bounds__(256) void k_prep(const float* __restrict__ hw1,
        const float* __restrict__ hw2, const float* __restrict__ ew2,
        const float* __restrict__ gw, u16* __restrict__ wb)
{
    int idx = blockIdx.x*256 + threadIdx.x;
    if (idx < 4096){
        int u = idx; int j=u&7; int o=(u>>3)&31; int kq=(u>>8)&3; int s=u>>10;
        int tap = 2*s + (kq>>1); int ic = (kq&1)*8 + j;
        wb[idx] = (tap<7) ? f2b(hw1[(o*16+ic)*7+tap]) : (u16)0;
    } else if (idx < 18432){
        int u = idx - 4096; int j=u&7; int o=(u>>3)&63; int kq=(u>>9)&3; int s=u>>11;
        wb[idx] = f2b(hw2[(o*32 + kq*8 + j)*7 + s]);
    } else if (idx < 75776){
        int u = idx - 18432; int j=u&7; int o=(u>>3)&127; int kq=(u>>10)&3; int s=u>>12;
        int ih = s/7, tap = s-ih*7;
        wb[idx] = f2b(ew2[(o*64 + ih*32 + kq*8 + j)*7 + tap]);
    } else if (idx < 92160){
        int u = idx - 75776; int j=u&7; int o=(u>>3)&63; int tb=(u>>9)&1; int gi=u>>10;
        int tap = tb*8 + j;
        wb[idx] = (tap<15) ? f2b(gw[gi*960 + o*15 + tap]) : (u16)0;
    }
}

// ---------------------------------------------------------------------------
// Hypernet conv1: x[128,16,12288] f32 -> h1 bf16 [b][3072 pos][32 ch].
// v4: (256,4) so prefetch regs stay live; sched_barrier pins load issue;
// output staged via LDS -> coalesced short8 stores (full 128B lines).
// ---------------------------------------------------------------------------
__global__ __launch_bounds__(256,4) void k_hconv1(const float* __restrict__ x,
        const u16* __restrict__ wb1, const float* __restrict__ bias,
        u16* __restrict__ h1)
{
    __shared__ __align__(16) u16 xs[2][264*24];
    __shared__ __align__(16) u16 ob[2][64*32];
    int b = blockIdx.x / 24, pb = blockIdx.x % 24;
    int tid = threadIdx.x;
    const float* xb = x + (size_t)b*16*12288;
    int wv = tid >> 6, lane = tid & 63;
    int m = lane & 15, kq = lane >> 4;
    int ohalf = wv & 1, thalf = wv >> 1;
    int o = ohalf*16 + m;

    short8 wfr[4];
    #pragma unroll
    for (int s=0;s<4;s++)
        wfr[s] = *reinterpret_cast<const short8*>(&wb1[(((s*4+kq)*32)+o)*8]);
    float bv = bias[o];

    float rg0[16]; float rgx;
    int exrow = 256 + (tid>>4), exch = tid & 15;

#define LOADTILE(G0) { \
        int t0 = refl((G0) - 3 + tid, 12288); \
        _Pragma("unroll") \
        for (int ic=0;ic<16;ic++) rg0[ic] = xb[(size_t)ic*12288 + t0]; \
        if (tid < 128){ \
            int t1 = refl((G0) - 3 + exrow, 12288); \
            rgx = xb[(size_t)exch*12288 + t1]; \
        } \
        __builtin_amdgcn_sched_barrier(0); }

#define WRITETILE(BUF) { \
        short8 p0, p1; \
        _Pragma("unroll") \
        for (int j=0;j<8;j++){ p0[j] = (short)f2b(rg0[j]); p1[j] = (short)f2b(rg0[8+j]); } \
        *reinterpret_cast<short8*>(&xs[BUF][tid*24])     = p0; \
        *reinterpret_cast<short8*>(&xs[BUF][tid*24 + 8]) = p1; \
        if (tid < 128) xs[BUF][exrow*24 + exch] = f2b(rgx); }

#define COMPUTETILE(BUF) { \
        floatx4 acc[8]; \
        _Pragma("unroll") \
        for (int i=0;i<8;i++) acc[i] = (floatx4){0.f,0.f,0.f,0.f}; \
        int tb0 = thalf*128; \
        _Pragma("unroll") \
        for (int sub=0; sub<8; sub++){ \
            int tb = tb0 + sub*16; \
            _Pragma("unroll") \
            for (int s=0;s<4;s++){ \
                int tap = 2*s + (kq>>1); \
                short8 xfr = *reinterpret_cast<const short8*>( \
                                &xs[BUF][(tb + m + tap)*24 + (kq&1)*8]); \
                acc[sub] = __builtin_amdgcn_mfma_f32_16x16x32_bf16(xfr, wfr[s], acc[sub], 0,0,0); \
            } \
        } \
        _Pragma("unroll") \
        for (int sub=0; sub<8; sub++){ \
            float sum = lk(acc[sub][0]+bv) + lk(acc[sub][1]+bv) \
                      + lk(acc[sub][2]+bv) + lk(acc[sub][3]+bv); \
            ob[BUF][(thalf*32 + sub*4 + kq)*32 + o] = f2b(sum*0.25f); \
        } }

#define STORETILE(BUF, TILE) { \
        short8 v = *reinterpret_cast<const short8*>(&ob[BUF][tid*8]); \
        *reinterpret_cast<short8*>(&h1[((size_t)b*3072 + (TILE)*64)*32 + tid*8]) = v; }

    int g0 = pb*512;
    LOADTILE(g0);
    WRITETILE(0);
    __syncthreads();
    LOADTILE(g0 + 256);
    COMPUTETILE(0);
    WRITETILE(1);
    __syncthreads();
    STORETILE(0, pb*2);
    COMPUTETILE(1);
    __syncthreads();
    STORETILE(1, pb*2 + 1);

#undef LOADTILE
#undef WRITETILE
#undef COMPUTETILE
#undef STORETILE
}

// ---------------------------------------------------------------------------
// Hypernet conv2: h1 bf16 [b][3072][32] -> h2 f32 [b][768 pos][64 ch].
// v3: pre-baked weight frags + sched_barrier load pinning.
// (f32 stores are already full 64B sectors -> no staging needed.)
// ---------------------------------------------------------------------------
__global__ __launch_bounds__(256,4) void k_hconv2(const u16* __restrict__ h1,
        const u16* __restrict__ wb2, const float* __restrict__ bias,
        float* __restrict__ h2)
{
    __shared__ __align__(16) u16 xs[2][198*40];
    int b = blockIdx.x >> 3, tile = blockIdx.x & 7;
    int tid = threadIdx.x;
    int wv = tid >> 6, lane = tid & 63;
    int m = lane & 15, kq = lane >> 4;
    int o = wv*16 + m;

    short8 wfr[7];
    #pragma unroll
    for (int s=0;s<7;s++)
        wfr[s] = *reinterpret_cast<const short8*>(&wb2[(((s*4+kq)*64)+o)*8]);
    float bv = bias[o];

    short8 rgA[3], rgX;

#define LOADH(HALF) { \
        int gh = tile*384 + (HALF)*192 - 3; \
        _Pragma("unroll") \
        for (int cc=0;cc<3;cc++){ \
            int c = tid + cc*256; \
            int row = c >> 2, q = c & 3; \
            int t = refl(gh + row, 3072); \
            rgA[cc] = *reinterpret_cast<const short8*>(&h1[((size_t)b*3072 + t)*32 + q*8]); \
        } \
        if (tid < 24){ \
            int c = 768 + tid; \
            int row = c >> 2, q = c & 3; \
            int t = refl(gh + row, 3072); \
            rgX = *reinterpret_cast<const short8*>(&h1[((size_t)b*3072 + t)*32 + q*8]); \
        } \
        __builtin_amdgcn_sched_barrier(0); }

#define WRITEH(BUF) { \
        _Pragma("unroll") \
        for (int cc=0;cc<3;cc++){ \
            int c = tid + cc*256; \
            *reinterpret_cast<short8*>(&xs[BUF][(c>>2)*40 + (c&3)*8]) = rgA[cc]; \
        } \
        if (tid < 24){ \
            int c = 768 + tid; \
            *reinterpret_cast<short8*>(&xs[BUF][(c>>2)*40 + (c&3)*8]) = rgX; \
        } }

#define COMPUTEH(BUF, HALF) { \
        floatx4 acc[12]; \
        _Pragma("unroll") \
        for (int i=0;i<12;i++) acc[i] = (floatx4){0.f,0.f,0.f,0.f}; \
        for (int sub=0; sub<12; sub++){ \
            int tb = sub*16; \
            _Pragma("unroll") \
            for (int s=0;s<7;s++){ \
                short8 xfr = *reinterpret_cast<const short8*>( \
                                &xs[BUF][(tb + m + s)*40 + kq*8]); \
                acc[sub] = __builtin_amdgcn_mfma_f32_16x16x32_bf16(xfr, wfr[s], acc[sub], 0,0,0); \
            } \
        } \
        _Pragma("unroll") \
        for (int sub=0; sub<12; sub++){ \
            float sum = lk(acc[sub][0]+bv) + lk(acc[sub][1]+bv) \
                      + lk(acc[sub][2]+bv) + lk(acc[sub][3]+bv); \
            h2[((size_t)b*768 + tile*96 + (HALF)*48 + sub*4 + kq)*64 + o] = sum*0.25f; \
        } }

    LOADH(0);
    WRITEH(0);
    __syncthreads();
    LOADH(1);
    COMPUTEH(0, 0);
    WRITEH(1);
    __syncthreads();
    COMPUTEH(1, 1);

#undef LOADH
#undef WRITEH
#undef COMPUTEH
}

// ---------------------------------------------------------------------------
// Hypernet conv3 FUSED: h2 f32 [b][768][64] -> latent[128,6144]. (unchanged)
// ---------------------------------------------------------------------------
__global__ __launch_bounds__(256) void k_hconv3(const float* __restrict__ h2,
        const float* __restrict__ w, const float* __restrict__ bias,
        float* __restrict__ latent)
{
    __shared__ float xs[64*201];
    int b = blockIdx.x >> 2, tile = blockIdx.x & 3;
    int g0 = tile*192;
    int tid = threadIdx.x;
    for (int idx = tid; idx < 198*64; idx += 256){
        int jj = idx >> 6, ic = idx & 63;
        int t = refl(g0 + jj - 3, 768);
        xs[ic*201 + jj] = h2[((size_t)b*768 + t)*64 + ic];
    }
    __syncthreads();
    int c = tid >> 5, run = tid & 31;
    int p0 = run*6;
    float acc[6];
    #pragma unroll
    for (int l=0;l<6;l++) acc[l] = 0.f;
    for (int ic=0; ic<64; ic++){
        const float* wp = w + (c*64+ic)*7;
        float wr[7];
        #pragma unroll
        for (int s=0;s<7;s++) wr[s] = wp[s];
        const float* xr = xs + ic*201 + p0;
        float xw[12];
        #pragma unroll
        for (int j=0;j<12;j++) xw[j] = xr[j];
        #pragma unroll
        for (int s=0;s<7;s++)
            #pragma unroll
            for (int l=0;l<6;l++) acc[l] += wr[s]*xw[l+s];
    }
    float bv = bias[c];
    float* op = latent + (size_t)b*6144 + c*768 + g0 + p0;
    #pragma unroll
    for (int l=0;l<6;l++) op[l] = tanhf(acc[l] + bv);
}

// ---------------------------------------------------------------------------
// t1 = leaky(latent @ hl1^T).  (unchanged)
// ---------------------------------------------------------------------------
__global__ __launch_bounds__(256) void k_lin1(const float* __restrict__ latent,
        const float* __restrict__ hl1, float* __restrict__ t1)
{
    __shared__ float ls[6144];
    int b = blockIdx.x / 6, ntile = blockIdx.x % 6;
    int tid = threadIdx.x;
    const float4* lp = reinterpret_cast<const float4*>(latent + (size_t)b*6144);
    float4* lsv = reinterpret_cast<float4*>(ls);
    for (int i = tid; i < 1536; i += 256) lsv[i] = lp[i];
    __syncthreads();
    int wv = tid >> 6, lane = tid & 63;
    #pragma unroll
    for (int nn=0; nn<4; nn++){
        int n = ntile*16 + wv*4 + nn;
        const float4* wp = reinterpret_cast<const float4*>(hl1 + (size_t)n*6144);
        float s = 0.f;
        #pragma unroll
        for (int j=0;j<24;j++){
            float4 q = wp[lane + 64*j];
            float4 l4 = lsv[lane + 64*j];
            s += l4.x*q.x + l4.y*q.y + l4.z*q.z + l4.w*q.w;
        }
        #pragma unroll
        for (int off=32; off; off>>=1) s += __shfl_down(s, off);
        if (lane==0) t1[b*96+n] = lk(s);
    }
}

// ---------------------------------------------------------------------------
// logits = t1 @ hl2^T; top-5; n0 = #(idx<6)   (unchanged)
// ---------------------------------------------------------------------------
__global__ __launch_bounds__(128) void k_topk(const float* __restrict__ t1,
        const float* __restrict__ hl2, int* __restrict__ idxb, float* __restrict__ n0f)
{
    __shared__ float lg[96];
    int b = blockIdx.x, n = threadIdx.x;
    if (n < 96){
        float s = 0.f;
        const float* tp = t1 + b*96;
        const float* wp = hl2 + n*96;
        for (int m=0;m<96;m++) s += tp[m]*wp[m];
        lg[n] = s;
    }
    __syncthreads();
    if (threadIdx.x == 0){
        unsigned long long u0=0ull, u1=0ull;
        float n0 = 0.f;
        for (int k=0;k<5;k++){
            float best = -3.4e38f; int bi = 0;
            for (int m=0;m<96;m++){
                bool used = m<64 ? ((u0>>m)&1ull) : ((u1>>(m-64))&1ull);
                if (!used && lg[m] > best){ best = lg[m]; bi = m; }
            }
            if (bi<64) u0 |= 1ull<<bi; else u1 |= 1ull<<(bi-64);
            idxb[b*5+k] = bi;
            if (bi < 6) n0 += 1.f;
        }
        n0f[b] = n0;
    }
}

// ---------------------------------------------------------------------------
// Grouped idx conv (MFMA), weights from pre-baked gwb.
// ---------------------------------------------------------------------------
__global__ __launch_bounds__(256,3) void k_gconv(const float* __restrict__ x,
        const int* __restrict__ idxb, const float* __restrict__ n0f,
        const u16* __restrict__ gwb, const float* __restrict__ gb0,
        u16* __restrict__ zp)
{
    __shared__ __align__(16) u16 xs[5][8][536];
    __shared__ int nidx[5];
    __shared__ float n0s;
    int b = blockIdx.x >> 2, qc = blockIdx.x & 3;
    int tid = threadIdx.x;
    int p0g = qc*512;

    if (tid < 5) nidx[tid] = idxb[b*5 + tid];
    if (tid == 5) n0s = n0f[b];
    __syncthreads();

    for (int cch = tid; cch < 5*134; cch += 256){
        int k = cch / 134, q = cch - k*134;
        const float* xrow = x + (size_t)b*196608 + (size_t)nidx[k]*2048;
        int base = p0g + q*4;
        u16 vb[4];
        if (base + 3 <= 2047){
            float4 a = *reinterpret_cast<const float4*>(xrow + base);
            vb[0]=f2b(a.x); vb[1]=f2b(a.y); vb[2]=f2b(a.z); vb[3]=f2b(a.w);
        } else {
            #pragma unroll
            for (int jj=0;jj<4;jj++){
                int ii = base+jj; if (ii > 2047) ii = 2047;
                vb[jj] = f2b(xrow[ii]);
            }
        }
        #pragma unroll
        for (int jj=0;jj<4;jj++){
            int gof = q*4 + jj;
            #pragma unroll
            for (int r=0;r<8;r++){
                int i = gof - r;
                if (i >= 0 && i < 528) xs[k][r][i] = vb[jj];
            }
        }
    }

    int wv = tid >> 6, lane = tid & 63;
    int m = lane & 15, kq = lane >> 4;
    int o = wv*16 + m;

    short8 wfr[3];
    #pragma unroll
    for (int c=0;c<3;c++){
        int kk = 2*c + (kq>>1);
        int kkc = kk < 5 ? kk : 4;
        int gi = nidx[kkc] / 6;
        short8 f = *reinterpret_cast<const short8*>(
                        &gwb[(((gi*2 + (kq&1))*64)+o)*8]);
        if (kk >= 5) f = (short8)(short)0;
        wfr[c] = f;
    }
    float bv = n0s * gb0[o];
    __syncthreads();

    int rr = m & 7, ibase = (m & 8) + (kq & 1)*8;
    for (int g8 = 0; g8 < 4; ++g8){
        floatx4 acc[8];
        #pragma unroll
        for (int i=0;i<8;i++) acc[i] = (floatx4){0.f,0.f,0.f,0.f};
        #pragma unroll
        for (int s8=0; s8<8; ++s8){
            int P = (g8*8 + s8)*16;
            #pragma unroll
            for (int c=0;c<3;c++){
                int kk = 2*c + (kq>>1);
                int kkc = kk < 5 ? kk : 4;
                short8 af = *reinterpret_cast<const short8*>(&xs[kkc][rr][P + ibase]);
                acc[s8] = __builtin_amdgcn_mfma_f32_16x16x32_bf16(af, wfr[c], acc[s8], 0,0,0);
            }
        }
        #pragma unroll
        for (int s8=0; s8<8; ++s8){
            int sub = g8*8 + s8;
            int Q = qc*128 + sub*4 + kq;
            if (Q < 508){
                float mx = fmaxf(fmaxf(lk(acc[s8][0]+bv), lk(acc[s8][1]+bv)),
                                 fmaxf(lk(acc[s8][2]+bv), lk(acc[s8][3]+bv)));
                zp[((size_t)b*508 + Q)*64 + o] = f2b(mx);
            }
        }
    }
}

// ---------------------------------------------------------------------------
// Encoder conv2 (MFMA): zp bf16 [b][508][64] -> p2 f32 [b][125][128].
// Weights from pre-baked wbe (28 short8 loads/thread instead of 224 scalar).
// ---------------------------------------------------------------------------
__global__ __launch_bounds__(256,1) void k_econv2(const u16* __restrict__ zp,
        const u16* __restrict__ wbe, const float* __restrict__ bias,
        float* __restrict__ p2)
{
    __shared__ __align__(16) u16 xs[118*72];
    int b = blockIdx.x / 5, tile = blockIdx.x % 5;
    int tid = threadIdx.x;
    for (int c = tid; c < 118*8; c += 256){
        int row = c >> 3, q = c & 7;
        int t = tile*100 + row; if (t > 507) t = 507;
        *reinterpret_cast<short8*>(&xs[row*72 + q*8]) =
            *reinterpret_cast<const short8*>(&zp[((size_t)b*508 + t)*64 + q*8]);
    }
    __syncthreads();
    int wv = tid >> 6, lane = tid & 63;
    int m = lane & 15, kq = lane >> 4;
    for (int half=0; half<2; half++){
        int ot = wv + 4*half;
        int o = ot*16 + m;
        short8 wfr[14];
        #pragma unroll
        for (int s=0;s<14;s++)
            wfr[s] = *reinterpret_cast<const short8*>(&wbe[(((s*4+kq)*128)+o)*8]);
        floatx4 acc[7];
        #pragma unroll
        for (int i=0;i<7;i++) acc[i] = (floatx4){0.f,0.f,0.f,0.f};
        #pragma unroll
        for (int sub=0; sub<7; sub++){
            #pragma unroll
            for (int s=0;s<14;s++){
                int tap = s%7, ih = s/7;
                short8 xfr = *reinterpret_cast<const short8*>(
                                &xs[(sub*16 + m + tap)*72 + ih*32 + kq*8]);
                acc[sub] = __builtin_amdgcn_mfma_f32_16x16x32_bf16(xfr, wfr[s], acc[sub], 0,0,0);
            }
        }
        float bv = bias[o];
        #pragma unroll
        for (int sub=0; sub<7; sub++){
            int pidx = sub*4 + kq;
            if (pidx < 25){
                float mx = fmaxf(fmaxf(lk(acc[sub][0]+bv), lk(acc[sub][1]+bv)),
                                 fmaxf(lk(acc[sub][2]+bv), lk(acc[sub][3]+bv)));
                p2[((size_t)b*125 + tile*25 + pidx)*128 + o] = mx;
            }
        }
    }
}

// ---------------------------------------------------------------------------
// Fused tail: sliding sums + feat + classifier + log_softmax. (unchanged)
// ---------------------------------------------------------------------------
__global__ __launch_bounds__(128) void k_tail(const float* __restrict__ p2,
        const float* __restrict__ w, const float* __restrict__ bias,
        const float* __restrict__ cw, const float* __restrict__ cb,
        float* __restrict__ out)
{
    __shared__ float ss[7][128];
    __shared__ float ft[128];
    __shared__ float lgs[5];
    int b = blockIdx.x, tid = threadIdx.x;

    {
        const float* pb = p2 + (size_t)b*125*128 + tid;
        float first6[6], last6[6];
        float c = 0.f;
        #pragma unroll
        for (int t=0;t<6;t++){ float v = pb[(size_t)t*128]; first6[t]=v; c+=v; }
        for (int t=6;t<119;t++) c += pb[(size_t)t*128];
        #pragma unroll
        for (int t=0;t<6;t++) last6[t] = pb[(size_t)(119+t)*128];
        ss[0][tid] = c;
        #pragma unroll
        for (int s=0;s<6;s++){ c = c - first6[s] + last6[s]; ss[s+1][tid] = c; }
    }
    __syncthreads();

    {
        const float* wp = w + (size_t)tid*896;
        float s = 0.f;
        for (int ic=0; ic<128; ic++){
            #pragma unroll
            for (int tp=0; tp<7; tp++)
                s += wp[ic*7+tp]*ss[tp][ic];
        }
        ft[tid] = s*(1.f/119.f) + bias[tid];
    }
    __syncthreads();

    if (tid < 5){
        float lg = cb[tid];
        const float* wp = cw + tid*128;
        for (int o=0;o<128;o++) lg += ft[o]*wp[o];
        lgs[tid] = lg;
    }
    __syncthreads();
    if (tid == 0){
        float mx = -3.4e38f;
        for (int c=0;c<5;c++) mx = fmaxf(mx, lgs[c]);
        float se = 0.f;
        for (int c=0;c<5;c++) se += expf(lgs[c]-mx);
        float lse = mx + logf(se);
        for (int c=0;c<5;c++) out[b*5+c] = lgs[c]-lse;
    }
}

extern "C" void kernel_launch(void* const* d_in, const int* in_sizes, int n_in,
                              void* d_out, int out_size, void* d_ws, size_t ws_size,
                              hipStream_t stream)
{
    const float* x   = (const float*)d_in[0];
    const float* hw1 = (const float*)d_in[2];
    const float* hb1 = (const float*)d_in[3];
    const float* hw2 = (const float*)d_in[4];
    const float* hb2 = (const float*)d_in[5];
    const float* hw3 = (const float*)d_in[6];
    const float* hb3 = (const float*)d_in[7];
    const float* hl1 = (const float*)d_in[8];
    const float* hl2 = (const float*)d_in[9];
    const float* gw  = (const float*)d_in[10];
    const float* gb0 = (const float*)d_in[11];
    const float* ew2 = (const float*)d_in[12];
    const float* eb2 = (const float*)d_in[13];
    const float* ew3 = (const float*)d_in[14];
    const float* eb3 = (const float*)d_in[15];
    const float* cw  = (const float*)d_in[16];
    const float* cb  = (const float*)d_in[17];
    float* out = (float*)d_out;

    float* f       = (float*)d_ws;
    float* latent  = f;                       // [0, 786432)
    float* t1      = f + 786432;              // 12,288 f
    int*   idxb    = (int*)(f + 806432);
    float* n0f     = f + 808432;
    u16*   zpb     = (u16*)(f + 810000);      // 4,161,536 u16 -> ends f+2,890,768
    u16*   wb      = (u16*)(f + 2900000);     // 92,160 u16 -> ends f+2,946,080
    float* h2      = f + 3932160;             // 6,291,456 f -> ends 10,223,616
    float* p2      = f + 5000000;             // inside h2 region, used after h2 dead
    u16*   h1b     = (u16*)(f + 10223616);    // 9,437,184 u16

    k_prep<<<360, 256, 0, stream>>>(hw1, hw2, ew2, gw, wb);
    k_hconv1<<<3072, 256, 0, stream>>>(x, wb, hb1, h1b);
    k_hconv2<<<1024, 256, 0, stream>>>(h1b, wb + 4096, hb2, h2);
    k_hconv3<<<512, 256, 0, stream>>>(h2, hw3, hb3, latent);
    k_lin1<<<768, 256, 0, stream>>>(latent, hl1, t1);
    k_topk<<<128, 128, 0, stream>>>(t1, hl2, idxb, n0f);
    k_gconv<<<512, 256, 0, stream>>>(x, idxb, n0f, wb + 75776, gb0, zpb);
    k_econv2<<<640, 256, 0, stream>>>(zpb, wb + 18432, eb2, p2);
    k_tail<<<128, 128, 0, stream>>>(p2, ew3, eb3, cw, cb, out);
}